// Round 7
// baseline (1542.448 us; speedup 1.0000x reference)
//
#include <hip/hip_runtime.h>
#include <math.h>

#define D 128
#define N_NODES 5000
#define WINDOW 10
#define N_TOTAL 50000
#define NE_INT 131072
#define NE_TMP 90000
#define NE_FWD (N_TOTAL - N_NODES)   // 45000
#define HID 1024

typedef short bf16x8 __attribute__((ext_vector_type(8)));
typedef float f32x4 __attribute__((ext_vector_type(4)));

#define SK 136   // 128 + 8 pad (GRU/readout LDS row stride)
#define SCAN_B 256

static __device__ __forceinline__ short f2bf(float f) {
    union { float f; unsigned u; } v; v.f = f;
    unsigned r = v.u + 0x7fffu + ((v.u >> 16) & 1u);   // RNE
    return (short)(r >> 16);
}
static __device__ __forceinline__ float bf2f(short s) {
    union { unsigned u; float f; } v;
    v.u = ((unsigned)(unsigned short)s) << 16;
    return v.f;
}

// ---------------- weight transpose + cvt: out[n*K+k] = bf16(in[k*N+n]) ----------------
__global__ void k_tcvt(const float* __restrict__ in, short* __restrict__ out, int K, int N) {
    int i = blockIdx.x * blockDim.x + threadIdx.x;
    if (i >= N * K) return;
    int n = i / K, k = i - n * K;
    out[i] = f2bf(in[(size_t)k * N + n]);
}

// ---------------- init h ----------------
__global__ void k_init_h(const int* __restrict__ nodes, const float* __restrict__ embed,
                         float* __restrict__ h32, short* __restrict__ h16) {
    int i = blockIdx.x * blockDim.x + threadIdx.x;
    if (i >= N_TOTAL * D) return;
    int row = i >> 7;
    int c = i & 127;
    int n = nodes[row / WINDOW];
    float v = embed[n * D + c];
    h32[i] = v;
    h16[i] = f2bf(v);
}

// ---------------- edge builders ----------------
__global__ void k_build_int_edges(const int* __restrict__ ie, int* __restrict__ src,
                                  int* __restrict__ dst, int* __restrict__ icnt) {
    int e = blockIdx.x * blockDim.x + threadIdx.x;
    if (e >= NE_INT) return;
    int t = ie[e * 3 + 0], a = ie[e * 3 + 1], b = ie[e * 3 + 2];
    int d = t * N_NODES + b;
    src[e] = t * N_NODES + a;
    dst[e] = d;
    atomicAdd(&icnt[d], 1);
}

__global__ void k_build_tmp_edges(int* __restrict__ src, int* __restrict__ dst) {
    int e = blockIdx.x * blockDim.x + threadIdx.x;
    if (e >= NE_TMP) return;
    int s, d;
    if (e < NE_FWD) { s = e; d = e + N_NODES; }
    else { int q = e - NE_FWD; s = q + N_NODES; d = q; }
    src[e] = s;
    dst[e] = d;
}

// ---------------- 3-kernel exclusive scan over icnt[N_TOTAL] -> rowstart ----------------
__global__ void k_scan_partial(const int* __restrict__ cnt, int* __restrict__ rowstart,
                               int* __restrict__ btot, int n) {
    __shared__ int s[SCAN_B];
    int tid = threadIdx.x;
    int i = blockIdx.x * SCAN_B + tid;
    int v = (i < n) ? cnt[i] : 0;
    s[tid] = v;
    __syncthreads();
    for (int off = 1; off < SCAN_B; off <<= 1) {
        int x = (tid >= off) ? s[tid - off] : 0;
        __syncthreads();
        s[tid] += x;
        __syncthreads();
    }
    if (i < n) rowstart[i] = s[tid] - v;   // block-local exclusive
    if (tid == SCAN_B - 1) btot[blockIdx.x] = s[tid];
}

__global__ void k_scan_block(int* __restrict__ btot, int nb) {
    __shared__ int s[SCAN_B];
    int tid = threadIdx.x;
    int v = (tid < nb) ? btot[tid] : 0;
    s[tid] = v;
    __syncthreads();
    for (int off = 1; off < SCAN_B; off <<= 1) {
        int x = (tid >= off) ? s[tid - off] : 0;
        __syncthreads();
        s[tid] += x;
        __syncthreads();
    }
    if (tid < nb) btot[tid] = s[tid] - v;  // exclusive block offsets
}

__global__ void k_scan_add(int* __restrict__ rowstart, const int* __restrict__ btot,
                           int* __restrict__ cursor, int n, int total) {
    int i = blockIdx.x * blockDim.x + threadIdx.x;
    if (i < n) {
        int v = rowstart[i] + btot[i >> 8];
        rowstart[i] = v;
        cursor[i] = v;
    }
    if (i == 0) rowstart[n] = total;
}

// perm[e] = position of edge e in CSR order (so GRU reads m contiguously)
__global__ void k_fill_csr(const int* __restrict__ dst, int nE, int* __restrict__ cursor,
                           int* __restrict__ perm) {
    int e = blockIdx.x * blockDim.x + threadIdx.x;
    if (e >= nE) return;
    int p = atomicAdd(&cursor[dst[e]], 1);
    perm[e] = p;
}

// ---------------- fused message MLP (MFMA), bf16 m output (CSR-permuted) ----------------
// 64 edges/block, hidden chunks of 256. GEMM1: wave owns 4 ch-tiles x 4 edge-tiles
// (each LDS read feeds 4 MFMAs). GEMM2: wave owns 2 edge-tiles x 4 out-tiles (same
// 4x reuse). Ain + single Hid, XOR-swizzled, 2 barriers/chunk.
__global__ void __launch_bounds__(256, 2) k_msg_mfma(
    const short* __restrict__ h16, const int* __restrict__ src, const int* __restrict__ dst,
    const int* __restrict__ perm, int nE,
    const short* __restrict__ W1T, const float* __restrict__ b1,
    const short* __restrict__ W2T, const float* __restrict__ b2,
    short* __restrict__ m)
{
    __shared__ short Ain[64 * 256];   // 32 KB, unit-swizzled
    __shared__ short Hid[64 * 256];   // 32 KB, unit-swizzled (256-ch chunk)

    int t = threadIdx.x;
    int e0 = blockIdx.x * 64;
    int w = t >> 6, lane = t & 63;
    int lm = lane & 15, lk = lane >> 4;

    // ---- gather once: 4 threads/edge ----
    {
        int r = t >> 2, q = t & 3;
        int e = e0 + r;
        int ec = (e < nE) ? e : (nE - 1);
        const uint4* ps = (const uint4*)(h16 + (size_t)src[ec] * D);
        const uint4* pd = (const uint4*)(h16 + (size_t)dst[ec] * D);
        uint4* ao = (uint4*)(Ain + r * 256);
#pragma unroll
        for (int i = 0; i < 8; ++i) {
            int u = q * 8 + i;
            uint4 v = (u < 16) ? ps[u] : pd[u - 16];
            int pu = (u & 16) | ((u ^ r) & 15);
            ao[pu] = v;
        }
    }
    __syncthreads();

    // GEMM2 accumulators: wave w -> edges {(w&1)*2, +1} x out-tiles {(w>>1)*4 .. +3}
    f32x4 c2[4][2];
#pragma unroll
    for (int j = 0; j < 4; ++j)
#pragma unroll
        for (int i = 0; i < 2; ++i)
#pragma unroll
            for (int rg = 0; rg < 4; ++rg) c2[j][i][rg] = 0.f;

    int eb = (w & 1) * 2;
    int ob = (w >> 1) * 4;

    for (int hc = 0; hc < 4; ++hc) {   // hidden chunks of 256
        // GEMM1: wave w computes ch-tiles w*4..w*4+3 x 4 edge-tiles, K=256
        f32x4 c1[4][4];
#pragma unroll
        for (int cs = 0; cs < 4; ++cs)
#pragma unroll
            for (int et = 0; et < 4; ++et)
#pragma unroll
                for (int rg = 0; rg < 4; ++rg) c1[cs][et][rg] = 0.f;
#pragma unroll
        for (int kk = 0; kk < 8; ++kk) {
            int ko = kk * 32 + lk * 8;
            bf16x8 a[4];
#pragma unroll
            for (int cs = 0; cs < 4; ++cs)
                a[cs] = *(const bf16x8*)(W1T + (size_t)(hc * 256 + (w * 4 + cs) * 16 + lm) * 256 + ko);
            int u = kk * 4 + lk;
            bf16x8 bf[4];
#pragma unroll
            for (int et = 0; et < 4; ++et) {
                int edge = et * 16 + lm;
                int pu = (u & 16) | ((u ^ edge) & 15);
                bf[et] = *(const bf16x8*)(Ain + edge * 256 + pu * 8);
            }
#pragma unroll
            for (int cs = 0; cs < 4; ++cs)
#pragma unroll
                for (int et = 0; et < 4; ++et)
                    c1[cs][et] = __builtin_amdgcn_mfma_f32_16x16x32_bf16(a[cs], bf[et], c1[cs][et], 0, 0, 0);
        }
        __syncthreads();   // previous chunk's GEMM2 Hid readers done
        // bias + relu + cvt -> swizzled Hid
#pragma unroll
        for (int cs = 0; cs < 4; ++cs) {
            int chl = (w * 4 + cs) * 16 + lk * 4;   // local hidden ch 0..255
            float4 bq = *(const float4*)(b1 + hc * 256 + chl);
            int qw = chl >> 3;          // unit 0..31
            int sub = chl & 7;
#pragma unroll
            for (int et = 0; et < 4; ++et) {
                int edge = et * 16 + lm;
                int pu = (qw & 16) | ((qw ^ (edge & 15)) & 15);
                short4 sv;
                sv.x = f2bf(fmaxf(c1[cs][et][0] + bq.x, 0.f));
                sv.y = f2bf(fmaxf(c1[cs][et][1] + bq.y, 0.f));
                sv.z = f2bf(fmaxf(c1[cs][et][2] + bq.z, 0.f));
                sv.w = f2bf(fmaxf(c1[cs][et][3] + bq.w, 0.f));
                *(short4*)(Hid + edge * 256 + pu * 8 + sub) = sv;
            }
        }
        __syncthreads();
        // GEMM2 accumulate: K-chunk 256 from swizzled Hid
#pragma unroll
        for (int kk = 0; kk < 8; ++kk) {
            int ko = kk * 32 + lk * 8;
            bf16x8 a2[4];
#pragma unroll
            for (int j = 0; j < 4; ++j)
                a2[j] = *(const bf16x8*)(W2T + (size_t)((ob + j) * 16 + lm) * 1024 + hc * 256 + ko);
            int u = kk * 4 + lk;
            bf16x8 b2f[2];
#pragma unroll
            for (int i = 0; i < 2; ++i) {
                int edge = (eb + i) * 16 + lm;
                int pu = (u & 16) | ((u ^ (edge & 15)) & 15);
                b2f[i] = *(const bf16x8*)(Hid + edge * 256 + pu * 8);
            }
#pragma unroll
            for (int j = 0; j < 4; ++j)
#pragma unroll
                for (int i = 0; i < 2; ++i)
                    c2[j][i] = __builtin_amdgcn_mfma_f32_16x16x32_bf16(a2[j], b2f[i], c2[j][i], 0, 0, 0);
        }
    }

    // ---- store: m[pos][ch] = relu(msg + b2); pos = perm[e] (CSR order) or e ----
#pragma unroll
    for (int i = 0; i < 2; ++i) {
        int edge = (eb + i) * 16 + lm;
        int e = e0 + edge;
        if (e >= nE) continue;
        int pos = perm ? perm[e] : e;
        short* rowp = m + (size_t)pos * 128;
#pragma unroll
        for (int j = 0; j < 4; ++j) {
            int out0 = (ob + j) * 16 + lk * 4;
            float4 bq = *(const float4*)(b2 + out0);
            short4 sv;
            sv.x = f2bf(fmaxf(c2[j][i][0] + bq.x, 0.f));
            sv.y = f2bf(fmaxf(c2[j][i][1] + bq.y, 0.f));
            sv.z = f2bf(fmaxf(c2[j][i][2] + bq.z, 0.f));
            sv.w = f2bf(fmaxf(c2[j][i][3] + bq.w, 0.f));
            *(short4*)(rowp + out0) = sv;
        }
    }
}

// ---------------- fused seg-mean (CSR-contiguous or temporal) + GRU (MFMA) ----------------
__global__ void __launch_bounds__(256, 2) k_gru_mfma(
    const short* __restrict__ m, const int* __restrict__ rowstart, int mode,
    float* __restrict__ h32, short* __restrict__ h16,
    const short* __restrict__ WT, const short* __restrict__ UT,
    const float* __restrict__ b)
{
    __shared__ short Ax[64 * SK];
    __shared__ short Hx[64 * SK];
    int t = threadIdx.x;
    int r0 = blockIdx.x * 64;

    {
        int r = t >> 2, q = t & 3;
        int row = r0 + r;
        int rc = (row < N_TOTAL) ? row : (N_TOTAL - 1);
        const uint4* hp = (const uint4*)(h16 + (size_t)rc * D);
        uint4* hxo = (uint4*)(Hx + r * SK);
#pragma unroll
        for (int i = 0; i < 4; ++i) hxo[q * 4 + i] = hp[q * 4 + i];

        float acc[32];
#pragma unroll
        for (int i = 0; i < 32; ++i) acc[i] = 0.f;
        int deg = 0;
        if (row < N_TOTAL) {
            if (mode == 0) {
                int s0 = rowstart[row], s1 = rowstart[row + 1];
                deg = s1 - s0;
                for (int p = s0; p < s1; ++p) {   // contiguous rows (CSR-ordered m)
                    const uint4* mp = (const uint4*)(m + (size_t)p * 128 + q * 32);
#pragma unroll
                    for (int i = 0; i < 4; ++i) {
                        uint4 v = mp[i];
                        const short* sp = (const short*)&v;
#pragma unroll
                        for (int j = 0; j < 8; ++j) acc[i * 8 + j] += bf2f(sp[j]);
                    }
                }
            } else {
                if (row >= N_NODES) {   // fwd edge e = row - N_NODES
                    const uint4* mp = (const uint4*)(m + (size_t)(row - N_NODES) * 128 + q * 32);
                    ++deg;
#pragma unroll
                    for (int i = 0; i < 4; ++i) {
                        uint4 v = mp[i];
                        const short* sp = (const short*)&v;
#pragma unroll
                        for (int j = 0; j < 8; ++j) acc[i * 8 + j] += bf2f(sp[j]);
                    }
                }
                if (row < NE_FWD) {     // bwd edge e = NE_FWD + row
                    const uint4* mp = (const uint4*)(m + (size_t)(NE_FWD + row) * 128 + q * 32);
                    ++deg;
#pragma unroll
                    for (int i = 0; i < 4; ++i) {
                        uint4 v = mp[i];
                        const short* sp = (const short*)&v;
#pragma unroll
                        for (int j = 0; j < 8; ++j) acc[i * 8 + j] += bf2f(sp[j]);
                    }
                }
            }
        }
        float inv = (deg > 0) ? 1.f / (float)deg : 0.f;
        uint4* axp = (uint4*)(Ax + r * SK + q * 32);
#pragma unroll
        for (int i = 0; i < 4; ++i) {
            union { uint4 u; short s[8]; } pk;
#pragma unroll
            for (int j = 0; j < 8; ++j) pk.s[j] = f2bf(acc[i * 8 + j] * inv);
            axp[i] = pk.u;
        }
    }
    __syncthreads();

    int w = t >> 6, lane = t & 63;
    int lm = lane & 15, lk = lane >> 4;

    for (int g = 0; g < 8; ++g) {
        int ch = g * 16 + lm;
        f32x4 cxz, cxr, cxh, chz, chr_, chh;
#pragma unroll
        for (int rg = 0; rg < 4; ++rg) {
            cxz[rg] = b[ch];        chz[rg] = b[384 + ch];
            cxr[rg] = b[128 + ch];  chr_[rg] = b[384 + 128 + ch];
            cxh[rg] = b[256 + ch];  chh[rg] = b[384 + 256 + ch];
        }
#pragma unroll
        for (int kk = 0; kk < 4; ++kk) {
            int ko = kk * 32 + lk * 8;
            bf16x8 ax = *(const bf16x8*)(Ax + (w * 16 + lm) * SK + ko);
            bf16x8 hx = *(const bf16x8*)(Hx + (w * 16 + lm) * SK + ko);
            bf16x8 bz = *(const bf16x8*)(WT + (size_t)(ch) * 128 + ko);
            bf16x8 br = *(const bf16x8*)(WT + (size_t)(128 + ch) * 128 + ko);
            bf16x8 bh = *(const bf16x8*)(WT + (size_t)(256 + ch) * 128 + ko);
            bf16x8 uz = *(const bf16x8*)(UT + (size_t)(ch) * 128 + ko);
            bf16x8 ur = *(const bf16x8*)(UT + (size_t)(128 + ch) * 128 + ko);
            bf16x8 uh = *(const bf16x8*)(UT + (size_t)(256 + ch) * 128 + ko);
            cxz = __builtin_amdgcn_mfma_f32_16x16x32_bf16(ax, bz, cxz, 0, 0, 0);
            cxr = __builtin_amdgcn_mfma_f32_16x16x32_bf16(ax, br, cxr, 0, 0, 0);
            cxh = __builtin_amdgcn_mfma_f32_16x16x32_bf16(ax, bh, cxh, 0, 0, 0);
            chz = __builtin_amdgcn_mfma_f32_16x16x32_bf16(hx, uz, chz, 0, 0, 0);
            chr_ = __builtin_amdgcn_mfma_f32_16x16x32_bf16(hx, ur, chr_, 0, 0, 0);
            chh = __builtin_amdgcn_mfma_f32_16x16x32_bf16(hx, uh, chh, 0, 0, 0);
        }
#pragma unroll
        for (int rg = 0; rg < 4; ++rg) {
            int row = r0 + w * 16 + lk * 4 + rg;
            if (row >= N_TOTAL) continue;
            float z = 1.f / (1.f + expf(-(cxz[rg] + chz[rg])));
            float r_ = 1.f / (1.f + expf(-(cxr[rg] + chr_[rg])));
            float hcv = tanhf(cxh[rg] + r_ * chh[rg]);
            size_t idx = (size_t)row * D + ch;
            float hold = h32[idx];
            float hnew = z * hold + (1.f - z) * hcv;
            h32[idx] = hnew;
            h16[idx] = f2bf(hnew);
        }
    }
}

// ---------------- generic MFMA GEMM: C = relu(A16 @ B + bias) ----------------
__global__ void __launch_bounds__(256, 2) k_ro_mfma(
    const short* __restrict__ A16, const short* __restrict__ BT,
    const float* __restrict__ bias, float* __restrict__ C32, short* __restrict__ C16,
    int M, int N, int K)
{
    __shared__ short As[64 * SK];
    int t = threadIdx.x;
    int mb = blockIdx.y * 64;
    int nb = blockIdx.x * 128;
    int w = t >> 6, lane = t & 63;
    int lm = lane & 15, lk = lane >> 4;

    f32x4 acc[8];
#pragma unroll
    for (int nt = 0; nt < 8; ++nt) {
        float bv = bias[nb + nt * 16 + lm];
        acc[nt][0] = bv; acc[nt][1] = bv; acc[nt][2] = bv; acc[nt][3] = bv;
    }

    for (int kc = 0; kc < K; kc += 128) {
        __syncthreads();
        {
            int r = t >> 2, q = t & 3;
            int row = mb + r;
            int rc = (row < M) ? row : (M - 1);
            const uint4* ap = (const uint4*)(A16 + (size_t)rc * K + kc);
            uint4* ao = (uint4*)(As + r * SK);
#pragma unroll
            for (int i = 0; i < 4; ++i) ao[q * 4 + i] = ap[q * 4 + i];
        }
        __syncthreads();
#pragma unroll
        for (int kk = 0; kk < 4; ++kk) {
            int ko = kk * 32 + lk * 8;
            bf16x8 a = *(const bf16x8*)(As + (w * 16 + lm) * SK + ko);
#pragma unroll
            for (int nt = 0; nt < 8; ++nt) {
                bf16x8 bfr = *(const bf16x8*)(BT + (size_t)(nb + nt * 16 + lm) * K + kc + ko);
                acc[nt] = __builtin_amdgcn_mfma_f32_16x16x32_bf16(a, bfr, acc[nt], 0, 0, 0);
            }
        }
    }
#pragma unroll
    for (int nt = 0; nt < 8; ++nt) {
        int col = nb + nt * 16 + lm;
#pragma unroll
        for (int rg = 0; rg < 4; ++rg) {
            int row = mb + w * 16 + lk * 4 + rg;
            if (row >= M) continue;
            float v = fmaxf(acc[nt][rg], 0.f);
            if (C32) C32[(size_t)row * N + col] = v;
            if (C16) C16[(size_t)row * N + col] = f2bf(v);
        }
    }
}

// ---------------- final 512x10 logits + softmax ----------------
__global__ void __launch_bounds__(64) k_logits_softmax(
    const float* __restrict__ r2, const float* __restrict__ W3,
    const float* __restrict__ b3, float* __restrict__ out)
{
    int row = blockIdx.x;
    int t = threadIdx.x;
    float p[10];
#pragma unroll
    for (int j = 0; j < 10; ++j) p[j] = 0.f;
    for (int k = t; k < 512; k += 64) {
        float v = r2[(size_t)row * 512 + k];
#pragma unroll
        for (int j = 0; j < 10; ++j) p[j] += v * W3[k * 10 + j];
    }
#pragma unroll
    for (int j = 0; j < 10; ++j) {
        float s = p[j];
        for (int off = 32; off > 0; off >>= 1) s += __shfl_down(s, off);
        p[j] = s;
    }
    if (t == 0) {
        float mx = -1e30f;
#pragma unroll
        for (int j = 0; j < 10; ++j) { p[j] += b3[j]; mx = fmaxf(mx, p[j]); }
        float sum = 0.f;
#pragma unroll
        for (int j = 0; j < 10; ++j) { p[j] = expf(p[j] - mx); sum += p[j]; }
        float inv = 1.f / sum;
#pragma unroll
        for (int j = 0; j < 10; ++j) out[(size_t)row * 10 + j] = p[j] * inv;
    }
}

extern "C" void kernel_launch(void* const* d_in, const int* in_sizes, int n_in,
                              void* d_out, int out_size, void* d_ws, size_t ws_size,
                              hipStream_t stream)
{
    const int*   ie    = (const int*)d_in[0];
    const int*   nodes = (const int*)d_in[1];
    const float* embed = (const float*)d_in[2];
    const float* mW1   = (const float*)d_in[3];
    const float* mb1   = (const float*)d_in[4];
    const float* mW2   = (const float*)d_in[5];
    const float* mb2   = (const float*)d_in[6];
    const float* giW   = (const float*)d_in[7];
    const float* giU   = (const float*)d_in[8];
    const float* gib   = (const float*)d_in[9];
    const float* gtW   = (const float*)d_in[10];
    const float* gtU   = (const float*)d_in[11];
    const float* gtb   = (const float*)d_in[12];
    const float* rW1   = (const float*)d_in[13];
    const float* rb1   = (const float*)d_in[14];
    const float* rW2   = (const float*)d_in[15];
    const float* rb2   = (const float*)d_in[16];
    const float* rW3   = (const float*)d_in[17];
    const float* rb3   = (const float*)d_in[18];
    float* out = (float*)d_out;

    char* ws = (char*)d_ws;
    size_t off = 0;
    auto alloc = [&](size_t bytes) {
        void* p = ws + off;
        off += (bytes + 255) & ~(size_t)255;
        return p;
    };
    float* h32   = (float*)alloc((size_t)N_TOTAL * D * 4);
    short* h16   = (short*)alloc((size_t)N_TOTAL * D * 2);
    short* m     = (short*)alloc((size_t)NE_INT * 128 * 2);   // edge messages, bf16
    int*   icnt  = (int*)alloc((size_t)N_TOTAL * 4);
    int*   rowst = (int*)alloc((size_t)(N_TOTAL + 1) * 4);
    int*   btot  = (int*)alloc(256 * 4);
    int*   curs  = (int*)alloc((size_t)N_TOTAL * 4);
    int*   perm  = (int*)alloc((size_t)NE_INT * 4);
    int*   srcA  = (int*)alloc((size_t)NE_INT * 4);
    int*   dstA  = (int*)alloc((size_t)NE_INT * 4);
    int*   srcT  = (int*)alloc((size_t)NE_TMP * 4);
    int*   dstT  = (int*)alloc((size_t)NE_TMP * 4);
    short* mW1T  = (short*)alloc((size_t)HID * 256 * 2);
    short* mW2T  = (short*)alloc((size_t)D * HID * 2);
    short* giWT  = (short*)alloc((size_t)384 * D * 2);
    short* giUT  = (short*)alloc((size_t)384 * D * 2);
    short* gtWT  = (short*)alloc((size_t)384 * D * 2);
    short* gtUT  = (short*)alloc((size_t)384 * D * 2);
    short* rW1T  = (short*)alloc((size_t)HID * D * 2);
    short* rW2T  = (short*)alloc((size_t)512 * HID * 2);
    short* r1_16 = (short*)alloc((size_t)N_NODES * HID * 2);
    float* r2_32 = (float*)alloc((size_t)N_NODES * 512 * 4);

    // weight repack
    auto tc = [&](const float* in, short* o, int K, int N) {
        k_tcvt<<<(N * K + 255) / 256, 256, 0, stream>>>(in, o, K, N);
    };
    tc(mW1, mW1T, 256, HID);
    tc(mW2, mW2T, HID, D);
    tc(giW, giWT, D, 384);
    tc(giU, giUT, D, 384);
    tc(gtW, gtWT, D, 384);
    tc(gtU, gtUT, D, 384);
    tc(rW1, rW1T, D, HID);
    tc(rW2, rW2T, HID, 512);

    // init + CSR build (edges static across iterations)
    hipMemsetAsync(icnt, 0, (size_t)N_TOTAL * 4, stream);
    k_init_h<<<(N_TOTAL * D + 255) / 256, 256, 0, stream>>>(nodes, embed, h32, h16);
    k_build_int_edges<<<(NE_INT + 255) / 256, 256, 0, stream>>>(ie, srcA, dstA, icnt);
    k_build_tmp_edges<<<(NE_TMP + 255) / 256, 256, 0, stream>>>(srcT, dstT);
    int nb = (N_TOTAL + SCAN_B - 1) / SCAN_B;   // 196
    k_scan_partial<<<nb, SCAN_B, 0, stream>>>(icnt, rowst, btot, N_TOTAL);
    k_scan_block<<<1, SCAN_B, 0, stream>>>(btot, nb);
    k_scan_add<<<nb, SCAN_B, 0, stream>>>(rowst, btot, curs, N_TOTAL, NE_INT);
    k_fill_csr<<<(NE_INT + 255) / 256, 256, 0, stream>>>(dstA, NE_INT, curs, perm);

    int gmsgA = (NE_INT + 63) / 64;
    int gmsgT = (NE_TMP + 63) / 64;
    int ggru = (N_TOTAL + 63) / 64;
    for (int it = 0; it < 2; ++it) {
        k_msg_mfma<<<gmsgA, 256, 0, stream>>>(h16, srcA, dstA, perm, NE_INT, mW1T, mb1, mW2T, mb2, m);
        k_gru_mfma<<<ggru, 256, 0, stream>>>(m, rowst, 0, h32, h16, giWT, giUT, gib);

        k_msg_mfma<<<gmsgT, 256, 0, stream>>>(h16, srcT, dstT, (const int*)nullptr, NE_TMP, mW1T, mb1, mW2T, mb2, m);
        k_gru_mfma<<<ggru, 256, 0, stream>>>(m, rowst, 1, h32, h16, gtWT, gtUT, gtb);
    }

    // readout
    dim3 g1(HID / 128, (N_NODES + 63) / 64);
    k_ro_mfma<<<g1, 256, 0, stream>>>(h16, rW1T, rb1, (float*)nullptr, r1_16, N_NODES, HID, D);
    dim3 g2(512 / 128, (N_NODES + 63) / 64);
    k_ro_mfma<<<g2, 256, 0, stream>>>(r1_16, rW2T, rb2, r2_32, (short*)nullptr, N_NODES, 512, HID);
    k_logits_softmax<<<N_NODES, 64, 0, stream>>>(r2_32, rW3, rb3, out);
}

// Round 8
// 1336.055 us; speedup vs baseline: 1.1545x; 1.1545x over previous
//
#include <hip/hip_runtime.h>
#include <math.h>

#define D 128
#define N_NODES 5000
#define WINDOW 10
#define N_TOTAL 50000
#define NE_INT 131072
#define NE_TMP 90000
#define NE_FWD (N_TOTAL - N_NODES)   // 45000
#define HID 1024

typedef short bf16x8 __attribute__((ext_vector_type(8)));
typedef float f32x4 __attribute__((ext_vector_type(4)));

#define SK 136   // 128 + 8 pad (GRU/readout LDS row stride)
#define SCAN_B 256

static __device__ __forceinline__ short f2bf(float f) {
    union { float f; unsigned u; } v; v.f = f;
    unsigned r = v.u + 0x7fffu + ((v.u >> 16) & 1u);   // RNE
    return (short)(r >> 16);
}
static __device__ __forceinline__ float bf2f(short s) {
    union { unsigned u; float f; } v;
    v.u = ((unsigned)(unsigned short)s) << 16;
    return v.f;
}

// ---------------- fused weight transpose+cvt for all 8 weight mats (1 launch) ----------------
// out[n*K+k] = bf16(in[k*N+n]); segments laid out back-to-back in thread-id space.
__global__ void k_tcvt_all(
    const float* __restrict__ mW1, const float* __restrict__ mW2,
    const float* __restrict__ giW, const float* __restrict__ giU,
    const float* __restrict__ gtW, const float* __restrict__ gtU,
    const float* __restrict__ rW1, const float* __restrict__ rW2,
    short* __restrict__ o0, short* __restrict__ o1, short* __restrict__ o2,
    short* __restrict__ o3, short* __restrict__ o4, short* __restrict__ o5,
    short* __restrict__ o6, short* __restrict__ o7)
{
    int i = blockIdx.x * blockDim.x + threadIdx.x;
    const float* in; short* out; int K, N, base;
    if      (i <  262144) { in = mW1; out = o0; K = 256;  N = 1024; base = 0; }
    else if (i <  393216) { in = mW2; out = o1; K = 1024; N = 128;  base = 262144; }
    else if (i <  442368) { in = giW; out = o2; K = 128;  N = 384;  base = 393216; }
    else if (i <  491520) { in = giU; out = o3; K = 128;  N = 384;  base = 442368; }
    else if (i <  540672) { in = gtW; out = o4; K = 128;  N = 384;  base = 491520; }
    else if (i <  589824) { in = gtU; out = o5; K = 128;  N = 384;  base = 540672; }
    else if (i <  720896) { in = rW1; out = o6; K = 128;  N = 1024; base = 589824; }
    else if (i < 1245184) { in = rW2; out = o7; K = 1024; N = 512;  base = 720896; }
    else return;
    int j = i - base;
    int n = j / K, k = j - n * K;
    out[j] = f2bf(in[(size_t)k * N + n]);
}

// ---------------- init h ----------------
__global__ void k_init_h(const int* __restrict__ nodes, const float* __restrict__ embed,
                         float* __restrict__ h32, short* __restrict__ h16) {
    int i = blockIdx.x * blockDim.x + threadIdx.x;
    if (i >= N_TOTAL * D) return;
    int row = i >> 7;
    int c = i & 127;
    int n = nodes[row / WINDOW];
    float v = embed[n * D + c];
    h32[i] = v;
    h16[i] = f2bf(v);
}

// ---------------- edge builders ----------------
__global__ void k_build_int_edges(const int* __restrict__ ie, int* __restrict__ src,
                                  int* __restrict__ dst, int* __restrict__ icnt) {
    int e = blockIdx.x * blockDim.x + threadIdx.x;
    if (e >= NE_INT) return;
    int t = ie[e * 3 + 0], a = ie[e * 3 + 1], b = ie[e * 3 + 2];
    int d = t * N_NODES + b;
    src[e] = t * N_NODES + a;
    dst[e] = d;
    atomicAdd(&icnt[d], 1);
}

__global__ void k_build_tmp_edges(int* __restrict__ src, int* __restrict__ dst) {
    int e = blockIdx.x * blockDim.x + threadIdx.x;
    if (e >= NE_TMP) return;
    int s, d;
    if (e < NE_FWD) { s = e; d = e + N_NODES; }
    else { int q = e - NE_FWD; s = q + N_NODES; d = q; }
    src[e] = s;
    dst[e] = d;
}

// ---------------- 3-kernel exclusive scan over icnt[N_TOTAL] -> rowstart ----------------
__global__ void k_scan_partial(const int* __restrict__ cnt, int* __restrict__ rowstart,
                               int* __restrict__ btot, int n) {
    __shared__ int s[SCAN_B];
    int tid = threadIdx.x;
    int i = blockIdx.x * SCAN_B + tid;
    int v = (i < n) ? cnt[i] : 0;
    s[tid] = v;
    __syncthreads();
    for (int off = 1; off < SCAN_B; off <<= 1) {
        int x = (tid >= off) ? s[tid - off] : 0;
        __syncthreads();
        s[tid] += x;
        __syncthreads();
    }
    if (i < n) rowstart[i] = s[tid] - v;   // block-local exclusive
    if (tid == SCAN_B - 1) btot[blockIdx.x] = s[tid];
}

__global__ void k_scan_block(int* __restrict__ btot, int nb) {
    __shared__ int s[SCAN_B];
    int tid = threadIdx.x;
    int v = (tid < nb) ? btot[tid] : 0;
    s[tid] = v;
    __syncthreads();
    for (int off = 1; off < SCAN_B; off <<= 1) {
        int x = (tid >= off) ? s[tid - off] : 0;
        __syncthreads();
        s[tid] += x;
        __syncthreads();
    }
    if (tid < nb) btot[tid] = s[tid] - v;  // exclusive block offsets
}

__global__ void k_scan_add(int* __restrict__ rowstart, const int* __restrict__ btot,
                           int* __restrict__ cursor, int n, int total) {
    int i = blockIdx.x * blockDim.x + threadIdx.x;
    if (i < n) {
        int v = rowstart[i] + btot[i >> 8];
        rowstart[i] = v;
        cursor[i] = v;
    }
    if (i == 0) rowstart[n] = total;
}

// perm[e] = position of edge e in CSR order (so GRU reads m contiguously)
__global__ void k_fill_csr(const int* __restrict__ dst, int nE, int* __restrict__ cursor,
                           int* __restrict__ perm) {
    int e = blockIdx.x * blockDim.x + threadIdx.x;
    if (e >= nE) return;
    int p = atomicAdd(&cursor[dst[e]], 1);
    perm[e] = p;
}

// ---------------- fused message MLP (MFMA), bf16 m output (CSR-permuted) ----------------
// 64 edges/block, r6 tiling (8 MFMA per 2-weight-load k-step), 48 KB LDS:
// Ain 32 KB (swizzled) + single Hid 16 KB (swizzled), 2 barriers/chunk.
// __launch_bounds__(256,3) -> 3 blocks/CU for latency hiding (bottleneck is
// L2 weight-load latency: per-chunk weight set 131 KB >> 32 KB L1).
__global__ void __launch_bounds__(256, 3) k_msg_mfma(
    const short* __restrict__ h16, const int* __restrict__ src, const int* __restrict__ dst,
    const int* __restrict__ perm, int nE,
    const short* __restrict__ W1T, const float* __restrict__ b1,
    const short* __restrict__ W2T, const float* __restrict__ b2,
    short* __restrict__ m)
{
    __shared__ short Ain[64 * 256];   // 32 KB, unit-swizzled
    __shared__ short Hid[64 * 128];   // 16 KB, unit-swizzled, single buffer

    int t = threadIdx.x;
    int e0 = blockIdx.x * 64;
    int w = t >> 6, lane = t & 63;
    int lm = lane & 15, lk = lane >> 4;

    // ---- gather once: 4 threads/edge ----
    {
        int r = t >> 2, q = t & 3;
        int e = e0 + r;
        int ec = (e < nE) ? e : (nE - 1);
        const uint4* ps = (const uint4*)(h16 + (size_t)src[ec] * D);
        const uint4* pd = (const uint4*)(h16 + (size_t)dst[ec] * D);
        uint4* ao = (uint4*)(Ain + r * 256);
#pragma unroll
        for (int i = 0; i < 8; ++i) {
            int u = q * 8 + i;
            uint4 v = (u < 16) ? ps[u] : pd[u - 16];
            int pu = (u & 16) | ((u ^ r) & 15);
            ao[pu] = v;
        }
    }
    __syncthreads();

    // persistent GEMM2 accumulators: wave w owns out channels [32w, 32w+32)
    f32x4 c2[2][4];
#pragma unroll
    for (int cs = 0; cs < 2; ++cs)
#pragma unroll
        for (int et = 0; et < 4; ++et)
#pragma unroll
            for (int rg = 0; rg < 4; ++rg) c2[cs][et][rg] = 0.f;

    for (int hc = 0; hc < 8; ++hc) {   // hidden chunks of 128
        // GEMM1: wave w computes ch-tiles {2w, 2w+1} x 4 edge-tiles, K=256
        f32x4 c1[2][4];
#pragma unroll
        for (int cs = 0; cs < 2; ++cs)
#pragma unroll
            for (int et = 0; et < 4; ++et)
#pragma unroll
                for (int rg = 0; rg < 4; ++rg) c1[cs][et][rg] = 0.f;
#pragma unroll
        for (int kk = 0; kk < 8; ++kk) {
            int ko = kk * 32 + lk * 8;
            bf16x8 a0 = *(const bf16x8*)(W1T + (size_t)(hc * 128 + (2 * w) * 16 + lm) * 256 + ko);
            bf16x8 a1 = *(const bf16x8*)(W1T + (size_t)(hc * 128 + (2 * w + 1) * 16 + lm) * 256 + ko);
            int u = kk * 4 + lk;
            bf16x8 bf[4];
#pragma unroll
            for (int et = 0; et < 4; ++et) {
                int edge = et * 16 + lm;
                int pu = (u & 16) | ((u ^ edge) & 15);
                bf[et] = *(const bf16x8*)(Ain + edge * 256 + pu * 8);
            }
#pragma unroll
            for (int et = 0; et < 4; ++et) {
                c1[0][et] = __builtin_amdgcn_mfma_f32_16x16x32_bf16(a0, bf[et], c1[0][et], 0, 0, 0);
                c1[1][et] = __builtin_amdgcn_mfma_f32_16x16x32_bf16(a1, bf[et], c1[1][et], 0, 0, 0);
            }
        }
        __syncthreads();   // previous chunk's GEMM2 Hid readers done
        // bias + relu + cvt -> swizzled Hid
#pragma unroll
        for (int cs = 0; cs < 2; ++cs) {
            int chl = (2 * w + cs) * 16 + lk * 4;   // local hidden ch 0..127
            float4 bq = *(const float4*)(b1 + hc * 128 + chl);
            int qw = chl >> 3;          // unit 0..15
            int sub = chl & 7;
#pragma unroll
            for (int et = 0; et < 4; ++et) {
                int edge = et * 16 + lm;
                short4 sv;
                sv.x = f2bf(fmaxf(c1[cs][et][0] + bq.x, 0.f));
                sv.y = f2bf(fmaxf(c1[cs][et][1] + bq.y, 0.f));
                sv.z = f2bf(fmaxf(c1[cs][et][2] + bq.z, 0.f));
                sv.w = f2bf(fmaxf(c1[cs][et][3] + bq.w, 0.f));
                *(short4*)(Hid + edge * 128 + ((qw ^ (edge & 15)) << 3) + sub) = sv;
            }
        }
        __syncthreads();
        // GEMM2 accumulate: K-chunk 128 from swizzled Hid
#pragma unroll
        for (int kk = 0; kk < 4; ++kk) {
            int ko = kk * 32 + lk * 8;
            bf16x8 a0 = *(const bf16x8*)(W2T + (size_t)(w * 32 + lm) * 1024 + hc * 128 + ko);
            bf16x8 a1 = *(const bf16x8*)(W2T + (size_t)(w * 32 + 16 + lm) * 1024 + hc * 128 + ko);
            int q = kk * 4 + lk;
#pragma unroll
            for (int et = 0; et < 4; ++et) {
                int edge = et * 16 + lm;
                bf16x8 bf = *(const bf16x8*)(Hid + edge * 128 + ((q ^ (edge & 15)) << 3));
                c2[0][et] = __builtin_amdgcn_mfma_f32_16x16x32_bf16(a0, bf, c2[0][et], 0, 0, 0);
                c2[1][et] = __builtin_amdgcn_mfma_f32_16x16x32_bf16(a1, bf, c2[1][et], 0, 0, 0);
            }
        }
    }

    // ---- store: m[pos][ch] = relu(msg + b2); pos = perm[e] (CSR order) or e ----
#pragma unroll
    for (int et = 0; et < 4; ++et) {
        int edge = et * 16 + lm;
        int e = e0 + edge;
        if (e >= nE) continue;
        int pos = perm ? perm[e] : e;
        short* rowp = m + (size_t)pos * 128;
#pragma unroll
        for (int cs = 0; cs < 2; ++cs) {
            int out0 = w * 32 + cs * 16 + lk * 4;
            float4 bq = *(const float4*)(b2 + out0);
            short4 sv;
            sv.x = f2bf(fmaxf(c2[cs][et][0] + bq.x, 0.f));
            sv.y = f2bf(fmaxf(c2[cs][et][1] + bq.y, 0.f));
            sv.z = f2bf(fmaxf(c2[cs][et][2] + bq.z, 0.f));
            sv.w = f2bf(fmaxf(c2[cs][et][3] + bq.w, 0.f));
            *(short4*)(rowp + out0) = sv;
        }
    }
}

// ---------------- fused seg-mean (CSR-contiguous or temporal) + GRU (MFMA) ----------------
__global__ void __launch_bounds__(256, 4) k_gru_mfma(
    const short* __restrict__ m, const int* __restrict__ rowstart, int mode,
    float* __restrict__ h32, short* __restrict__ h16,
    const short* __restrict__ WT, const short* __restrict__ UT,
    const float* __restrict__ b)
{
    __shared__ short Ax[64 * SK];
    __shared__ short Hx[64 * SK];
    int t = threadIdx.x;
    int r0 = blockIdx.x * 64;

    {
        int r = t >> 2, q = t & 3;
        int row = r0 + r;
        int rc = (row < N_TOTAL) ? row : (N_TOTAL - 1);
        const uint4* hp = (const uint4*)(h16 + (size_t)rc * D);
        uint4* hxo = (uint4*)(Hx + r * SK);
#pragma unroll
        for (int i = 0; i < 4; ++i) hxo[q * 4 + i] = hp[q * 4 + i];

        float acc[32];
#pragma unroll
        for (int i = 0; i < 32; ++i) acc[i] = 0.f;
        int deg = 0;
        if (row < N_TOTAL) {
            if (mode == 0) {
                int s0 = rowstart[row], s1 = rowstart[row + 1];
                deg = s1 - s0;
                for (int p = s0; p < s1; ++p) {   // contiguous rows (CSR-ordered m)
                    const uint4* mp = (const uint4*)(m + (size_t)p * 128 + q * 32);
#pragma unroll
                    for (int i = 0; i < 4; ++i) {
                        uint4 v = mp[i];
                        const short* sp = (const short*)&v;
#pragma unroll
                        for (int j = 0; j < 8; ++j) acc[i * 8 + j] += bf2f(sp[j]);
                    }
                }
            } else {
                if (row >= N_NODES) {   // fwd edge e = row - N_NODES
                    const uint4* mp = (const uint4*)(m + (size_t)(row - N_NODES) * 128 + q * 32);
                    ++deg;
#pragma unroll
                    for (int i = 0; i < 4; ++i) {
                        uint4 v = mp[i];
                        const short* sp = (const short*)&v;
#pragma unroll
                        for (int j = 0; j < 8; ++j) acc[i * 8 + j] += bf2f(sp[j]);
                    }
                }
                if (row < NE_FWD) {     // bwd edge e = NE_FWD + row
                    const uint4* mp = (const uint4*)(m + (size_t)(NE_FWD + row) * 128 + q * 32);
                    ++deg;
#pragma unroll
                    for (int i = 0; i < 4; ++i) {
                        uint4 v = mp[i];
                        const short* sp = (const short*)&v;
#pragma unroll
                        for (int j = 0; j < 8; ++j) acc[i * 8 + j] += bf2f(sp[j]);
                    }
                }
            }
        }
        float inv = (deg > 0) ? 1.f / (float)deg : 0.f;
        uint4* axp = (uint4*)(Ax + r * SK + q * 32);
#pragma unroll
        for (int i = 0; i < 4; ++i) {
            union { uint4 u; short s[8]; } pk;
#pragma unroll
            for (int j = 0; j < 8; ++j) pk.s[j] = f2bf(acc[i * 8 + j] * inv);
            axp[i] = pk.u;
        }
    }
    __syncthreads();

    int w = t >> 6, lane = t & 63;
    int lm = lane & 15, lk = lane >> 4;

    for (int g = 0; g < 8; ++g) {
        int ch = g * 16 + lm;
        f32x4 cxz, cxr, cxh, chz, chr_, chh;
#pragma unroll
        for (int rg = 0; rg < 4; ++rg) {
            cxz[rg] = b[ch];        chz[rg] = b[384 + ch];
            cxr[rg] = b[128 + ch];  chr_[rg] = b[384 + 128 + ch];
            cxh[rg] = b[256 + ch];  chh[rg] = b[384 + 256 + ch];
        }
#pragma unroll
        for (int kk = 0; kk < 4; ++kk) {
            int ko = kk * 32 + lk * 8;
            bf16x8 ax = *(const bf16x8*)(Ax + (w * 16 + lm) * SK + ko);
            bf16x8 hx = *(const bf16x8*)(Hx + (w * 16 + lm) * SK + ko);
            bf16x8 bz = *(const bf16x8*)(WT + (size_t)(ch) * 128 + ko);
            bf16x8 br = *(const bf16x8*)(WT + (size_t)(128 + ch) * 128 + ko);
            bf16x8 bh = *(const bf16x8*)(WT + (size_t)(256 + ch) * 128 + ko);
            bf16x8 uz = *(const bf16x8*)(UT + (size_t)(ch) * 128 + ko);
            bf16x8 ur = *(const bf16x8*)(UT + (size_t)(128 + ch) * 128 + ko);
            bf16x8 uh = *(const bf16x8*)(UT + (size_t)(256 + ch) * 128 + ko);
            cxz = __builtin_amdgcn_mfma_f32_16x16x32_bf16(ax, bz, cxz, 0, 0, 0);
            cxr = __builtin_amdgcn_mfma_f32_16x16x32_bf16(ax, br, cxr, 0, 0, 0);
            cxh = __builtin_amdgcn_mfma_f32_16x16x32_bf16(ax, bh, cxh, 0, 0, 0);
            chz = __builtin_amdgcn_mfma_f32_16x16x32_bf16(hx, uz, chz, 0, 0, 0);
            chr_ = __builtin_amdgcn_mfma_f32_16x16x32_bf16(hx, ur, chr_, 0, 0, 0);
            chh = __builtin_amdgcn_mfma_f32_16x16x32_bf16(hx, uh, chh, 0, 0, 0);
        }
#pragma unroll
        for (int rg = 0; rg < 4; ++rg) {
            int row = r0 + w * 16 + lk * 4 + rg;
            if (row >= N_TOTAL) continue;
            float z = 1.f / (1.f + expf(-(cxz[rg] + chz[rg])));
            float r_ = 1.f / (1.f + expf(-(cxr[rg] + chr_[rg])));
            float hcv = tanhf(cxh[rg] + r_ * chh[rg]);
            size_t idx = (size_t)row * D + ch;
            float hold = h32[idx];
            float hnew = z * hold + (1.f - z) * hcv;
            h32[idx] = hnew;
            h16[idx] = f2bf(hnew);
        }
    }
}

// ---------------- generic MFMA GEMM: C = relu(A16 @ B + bias) ----------------
__global__ void __launch_bounds__(256, 2) k_ro_mfma(
    const short* __restrict__ A16, const short* __restrict__ BT,
    const float* __restrict__ bias, float* __restrict__ C32, short* __restrict__ C16,
    int M, int N, int K)
{
    __shared__ short As[64 * SK];
    int t = threadIdx.x;
    int mb = blockIdx.y * 64;
    int nb = blockIdx.x * 128;
    int w = t >> 6, lane = t & 63;
    int lm = lane & 15, lk = lane >> 4;

    f32x4 acc[8];
#pragma unroll
    for (int nt = 0; nt < 8; ++nt) {
        float bv = bias[nb + nt * 16 + lm];
        acc[nt][0] = bv; acc[nt][1] = bv; acc[nt][2] = bv; acc[nt][3] = bv;
    }

    for (int kc = 0; kc < K; kc += 128) {
        __syncthreads();
        {
            int r = t >> 2, q = t & 3;
            int row = mb + r;
            int rc = (row < M) ? row : (M - 1);
            const uint4* ap = (const uint4*)(A16 + (size_t)rc * K + kc);
            uint4* ao = (uint4*)(As + r * SK);
#pragma unroll
            for (int i = 0; i < 4; ++i) ao[q * 4 + i] = ap[q * 4 + i];
        }
        __syncthreads();
#pragma unroll
        for (int kk = 0; kk < 4; ++kk) {
            int ko = kk * 32 + lk * 8;
            bf16x8 a = *(const bf16x8*)(As + (w * 16 + lm) * SK + ko);
#pragma unroll
            for (int nt = 0; nt < 8; ++nt) {
                bf16x8 bfr = *(const bf16x8*)(BT + (size_t)(nb + nt * 16 + lm) * K + kc + ko);
                acc[nt] = __builtin_amdgcn_mfma_f32_16x16x32_bf16(a, bfr, acc[nt], 0, 0, 0);
            }
        }
    }
#pragma unroll
    for (int nt = 0; nt < 8; ++nt) {
        int col = nb + nt * 16 + lm;
#pragma unroll
        for (int rg = 0; rg < 4; ++rg) {
            int row = mb + w * 16 + lk * 4 + rg;
            if (row >= M) continue;
            float v = fmaxf(acc[nt][rg], 0.f);
            if (C32) C32[(size_t)row * N + col] = v;
            if (C16) C16[(size_t)row * N + col] = f2bf(v);
        }
    }
}

// ---------------- final 512x10 logits + softmax ----------------
__global__ void __launch_bounds__(64) k_logits_softmax(
    const float* __restrict__ r2, const float* __restrict__ W3,
    const float* __restrict__ b3, float* __restrict__ out)
{
    int row = blockIdx.x;
    int t = threadIdx.x;
    float p[10];
#pragma unroll
    for (int j = 0; j < 10; ++j) p[j] = 0.f;
    for (int k = t; k < 512; k += 64) {
        float v = r2[(size_t)row * 512 + k];
#pragma unroll
        for (int j = 0; j < 10; ++j) p[j] += v * W3[k * 10 + j];
    }
#pragma unroll
    for (int j = 0; j < 10; ++j) {
        float s = p[j];
        for (int off = 32; off > 0; off >>= 1) s += __shfl_down(s, off);
        p[j] = s;
    }
    if (t == 0) {
        float mx = -1e30f;
#pragma unroll
        for (int j = 0; j < 10; ++j) { p[j] += b3[j]; mx = fmaxf(mx, p[j]); }
        float sum = 0.f;
#pragma unroll
        for (int j = 0; j < 10; ++j) { p[j] = expf(p[j] - mx); sum += p[j]; }
        float inv = 1.f / sum;
#pragma unroll
        for (int j = 0; j < 10; ++j) out[(size_t)row * 10 + j] = p[j] * inv;
    }
}

extern "C" void kernel_launch(void* const* d_in, const int* in_sizes, int n_in,
                              void* d_out, int out_size, void* d_ws, size_t ws_size,
                              hipStream_t stream)
{
    const int*   ie    = (const int*)d_in[0];
    const int*   nodes = (const int*)d_in[1];
    const float* embed = (const float*)d_in[2];
    const float* mW1   = (const float*)d_in[3];
    const float* mb1   = (const float*)d_in[4];
    const float* mW2   = (const float*)d_in[5];
    const float* mb2   = (const float*)d_in[6];
    const float* giW   = (const float*)d_in[7];
    const float* giU   = (const float*)d_in[8];
    const float* gib   = (const float*)d_in[9];
    const float* gtW   = (const float*)d_in[10];
    const float* gtU   = (const float*)d_in[11];
    const float* gtb   = (const float*)d_in[12];
    const float* rW1   = (const float*)d_in[13];
    const float* rb1   = (const float*)d_in[14];
    const float* rW2   = (const float*)d_in[15];
    const float* rb2   = (const float*)d_in[16];
    const float* rW3   = (const float*)d_in[17];
    const float* rb3   = (const float*)d_in[18];
    float* out = (float*)d_out;

    char* ws = (char*)d_ws;
    size_t off = 0;
    auto alloc = [&](size_t bytes) {
        void* p = ws + off;
        off += (bytes + 255) & ~(size_t)255;
        return p;
    };
    float* h32   = (float*)alloc((size_t)N_TOTAL * D * 4);
    short* h16   = (short*)alloc((size_t)N_TOTAL * D * 2);
    short* m     = (short*)alloc((size_t)NE_INT * 128 * 2);   // edge messages, bf16
    int*   icnt  = (int*)alloc((size_t)N_TOTAL * 4);
    int*   rowst = (int*)alloc((size_t)(N_TOTAL + 1) * 4);
    int*   btot  = (int*)alloc(256 * 4);
    int*   curs  = (int*)alloc((size_t)N_TOTAL * 4);
    int*   perm  = (int*)alloc((size_t)NE_INT * 4);
    int*   srcA  = (int*)alloc((size_t)NE_INT * 4);
    int*   dstA  = (int*)alloc((size_t)NE_INT * 4);
    int*   srcT  = (int*)alloc((size_t)NE_TMP * 4);
    int*   dstT  = (int*)alloc((size_t)NE_TMP * 4);
    short* mW1T  = (short*)alloc((size_t)HID * 256 * 2);
    short* mW2T  = (short*)alloc((size_t)D * HID * 2);
    short* giWT  = (short*)alloc((size_t)384 * D * 2);
    short* giUT  = (short*)alloc((size_t)384 * D * 2);
    short* gtWT  = (short*)alloc((size_t)384 * D * 2);
    short* gtUT  = (short*)alloc((size_t)384 * D * 2);
    short* rW1T  = (short*)alloc((size_t)HID * D * 2);
    short* rW2T  = (short*)alloc((size_t)512 * HID * 2);
    short* r1_16 = (short*)alloc((size_t)N_NODES * HID * 2);
    float* r2_32 = (float*)alloc((size_t)N_NODES * 512 * 4);

    // weight repack (single fused launch)
    k_tcvt_all<<<(1245184 + 255) / 256, 256, 0, stream>>>(
        mW1, mW2, giW, giU, gtW, gtU, rW1, rW2,
        mW1T, mW2T, giWT, giUT, gtWT, gtUT, rW1T, rW2T);

    // init + CSR build (edges static across iterations)
    hipMemsetAsync(icnt, 0, (size_t)N_TOTAL * 4, stream);
    k_init_h<<<(N_TOTAL * D + 255) / 256, 256, 0, stream>>>(nodes, embed, h32, h16);
    k_build_int_edges<<<(NE_INT + 255) / 256, 256, 0, stream>>>(ie, srcA, dstA, icnt);
    k_build_tmp_edges<<<(NE_TMP + 255) / 256, 256, 0, stream>>>(srcT, dstT);
    int nb = (N_TOTAL + SCAN_B - 1) / SCAN_B;   // 196
    k_scan_partial<<<nb, SCAN_B, 0, stream>>>(icnt, rowst, btot, N_TOTAL);
    k_scan_block<<<1, SCAN_B, 0, stream>>>(btot, nb);
    k_scan_add<<<nb, SCAN_B, 0, stream>>>(rowst, btot, curs, N_TOTAL, NE_INT);
    k_fill_csr<<<(NE_INT + 255) / 256, 256, 0, stream>>>(dstA, NE_INT, curs, perm);

    int gmsgA = (NE_INT + 63) / 64;
    int gmsgT = (NE_TMP + 63) / 64;
    int ggru = (N_TOTAL + 63) / 64;
    for (int it = 0; it < 2; ++it) {
        k_msg_mfma<<<gmsgA, 256, 0, stream>>>(h16, srcA, dstA, perm, NE_INT, mW1T, mb1, mW2T, mb2, m);
        k_gru_mfma<<<ggru, 256, 0, stream>>>(m, rowst, 0, h32, h16, giWT, giUT, gib);

        k_msg_mfma<<<gmsgT, 256, 0, stream>>>(h16, srcT, dstT, (const int*)nullptr, NE_TMP, mW1T, mb1, mW2T, mb2, m);
        k_gru_mfma<<<ggru, 256, 0, stream>>>(m, rowst, 1, h32, h16, gtWT, gtUT, gtb);
    }

    // readout
    dim3 g1(HID / 128, (N_NODES + 63) / 64);
    k_ro_mfma<<<g1, 256, 0, stream>>>(h16, rW1T, rb1, (float*)nullptr, r1_16, N_NODES, HID, D);
    dim3 g2(512 / 128, (N_NODES + 63) / 64);
    k_ro_mfma<<<g2, 256, 0, stream>>>(r1_16, rW2T, rb2, r2_32, (short*)nullptr, N_NODES, 512, HID);
    k_logits_softmax<<<N_NODES, 64, 0, stream>>>(r2_32, rW3, rb3, out);
}